// Round 3
// baseline (419.632 us; speedup 1.0000x reference)
//
#include <hip/hip_runtime.h>
#include <math.h>

#define TOKENS   8192
#define HIDDEN   7168
#define NEXPERT  256
#define NGROUP   8
#define TOPKG    4
#define TOPK     8
#define SCALE    2.5f

// R9: structural rewrite of the gate GEMM to a 4-phase barrier-pipelined
// schedule (m201-style template adapted to N=256).
//   BM=128 x BN=256 (full N) per block, KSPLIT=4 -> grid 256 = 1 block/CU.
//   512 threads = 8 waves (2M x 4N), wave tile 64x64, mfma_f32_32x32x16_f16
//   (2382 vs 2075 TF ubench -> ~17% less matrix-pipe time than 16x16x32,
//   half the MFMA instructions). Same fp16 hi/lo 3-product numerics.
// Per K-tile (BK=32): 4 phases, one C-quadrant (i,j) each:
//   {ds_read frags; staging slice; barrier; setprio1; 6 MFMA; setprio0; barrier}
// Next-tile global loads issue in Ph0 (register-destined -> NOT drained at
// barriers, the R7/R8 lesson), consumed Ph2 (B->LDS) / Ph3 (A cvt->LDS).
// LDS 108 KB double-buffered. Split-K via atomicAdd into d_out (R3-proven).
#define BM 128
#define BN 256
#define BK 32
#define KSPLIT 4
#define KPB (HIDDEN / KSPLIT)   // 1792
#define NT  (KPB / BK)          // 56
#define WTILE_BYTES 32768       // W image tile: 256 rows x 4 octets x 32 B

// LDS layout (halves): addr(row,k,hl) = row*RSTR + (k>>3)*16 + hl*8 + (k&7).
// Row stride 72 halves = 144 B; each k-octet is (hi8|lo8) = 32 B contiguous.
// b128 frag reads / staged writes sit at the 8-lanes-per-start-bank wave64
// floor (R7 analysis: layout-independent for 16B-aligned b128).
#define RSTR 72

typedef _Float16 half8   __attribute__((ext_vector_type(8)));
typedef float    floatx16 __attribute__((ext_vector_type(16)));

// fp32x8 -> fp16 hi/lo split (RNE; identical bits to the proven R6/R8 path).
// logit = sum al*bh + ah*bl + ah*bh in fp32 MFMA acc; dropped al*bl ~ 2^-22.
__device__ __forceinline__ void cvt8(const float4 a, const float4 b,
                                     half8& h, half8& l) {
    h[0] = (_Float16)a.x; h[1] = (_Float16)a.y;
    h[2] = (_Float16)a.z; h[3] = (_Float16)a.w;
    h[4] = (_Float16)b.x; h[5] = (_Float16)b.y;
    h[6] = (_Float16)b.z; h[7] = (_Float16)b.w;
    l[0] = (_Float16)(a.x - (float)h[0]); l[1] = (_Float16)(a.y - (float)h[1]);
    l[2] = (_Float16)(a.z - (float)h[2]); l[3] = (_Float16)(a.w - (float)h[3]);
    l[4] = (_Float16)(b.x - (float)h[4]); l[5] = (_Float16)(b.y - (float)h[5]);
    l[6] = (_Float16)(b.z - (float)h[6]); l[7] = (_Float16)(b.w - (float)h[7]);
}

// ---------------------------------------------------------------------------
// zero d_out (poisoned 0xAA each iteration; atomic accumulation needs 0 init)
// ---------------------------------------------------------------------------
__global__ __launch_bounds__(256) void zero_kernel(float* __restrict__ O) {
    const int i = blockIdx.x * 256 + threadIdx.x;
    *(float4*)&O[(size_t)i * 4] = float4{0.f, 0.f, 0.f, 0.f};
}

// ---------------------------------------------------------------------------
// W pre-split: fp32 [256,7168] -> packed fp16 hi/lo tiles in d_ws.
// Tile (kz,t): ALL 256 experts x 4 k-octets x (hi8|lo8) = 32 KB, matching
// the GEMM's B-staging reads exactly. One block/expert, 896 threads.
// ---------------------------------------------------------------------------
__global__ __launch_bounds__(896) void wsplit_kernel(
    const float* __restrict__ W, char* __restrict__ WS)
{
    const int e  = blockIdx.x;          // expert 0..255
    const int og = threadIdx.x;         // k-octet within expert, 0..895
    const float4 a = *(const float4*)&W[(size_t)e * HIDDEN + og * 8];
    const float4 b = *(const float4*)&W[(size_t)e * HIDDEN + og * 8 + 4];
    half8 h, l;
    cvt8(a, b, h, l);

    const int kz = og / 224;            // k-split  0..3  (224 octets per kz)
    const int tt = (og % 224) >> 2;     // k-tile   0..55
    const int oc = og & 3;              // octet    0..3
    char* p = WS + (size_t)(kz * NT + tt) * WTILE_BYTES + (e * 4 + oc) * 32;
    *(half8*)p        = h;
    *(half8*)(p + 16) = l;
}

// ---------------------------------------------------------------------------
// Gate GEMM, 4-phase pipelined. Fragment layouts (gfx950 32x32x16_f16):
//   A: lane l -> row = l&31, k = (l>>5)*8 + e  (8 contiguous halves)
//   B: lane l -> col = l&31, k = (l>>5)*8 + e
//   D: col = lane&31, row = (reg&3) + 8*(reg>>2) + 4*(lane>>5)  [m74/m101]
// ---------------------------------------------------------------------------
__global__ __launch_bounds__(512, 2) void gate_gemm_kernel(
    const float* __restrict__ X, const char* __restrict__ WS,
    float* __restrict__ OUT)
{
    __shared__ _Float16 Ab[2][BM * RSTR];   // 2 x 18 KB
    __shared__ _Float16 Bb[2][BN * RSTR];   // 2 x 36 KB  -> 108 KB total

    const int tid = threadIdx.x;
    const int mb  = blockIdx.x * BM;        // 64 M-blocks
    const int kb  = blockIdx.y * KPB;       // 4 K-splits

    // A staging: thread -> (row = tid>>2 in 0..127, octet = tid&3); 32 B fp32
    // load (2 x float4), cvt8, one (hi8|lo8) pair into LDS.
    const int arow = tid >> 2, aoct = tid & 3;
    const float* Aptr = X + (size_t)(mb + arow) * HIDDEN + kb + aoct * 8;
    const int alb = arow * RSTR + aoct * 16;

    // B staging: pairs p = tid, tid+512 -> (row = p>>2 in 0..255, oct = p&3);
    // 32 B (hi8|lo8) contiguous in the packed W image -> 2 b128 LDS writes.
    const char* Wimg = WS + (size_t)blockIdx.y * NT * WTILE_BYTES;
    const int boff0 = tid * 32;
    const int boff1 = (tid + 512) * 32;
    const int blb0  = (tid >> 2) * RSTR + (tid & 3) * 16;
    const int blb1  = ((tid >> 2) + 128) * RSTR + (tid & 3) * 16;

    // 8 waves as 2M x 4N; wave tile 64x64 = 2x2 frags of 32x32
    const int lane = tid & 63, wave = tid >> 6;
    const int wm  = (wave >> 2) * 64;       // 0, 64
    const int wn  = (wave & 3) * 64;        // 0, 64, 128, 192
    const int r32 = lane & 31;
    const int kb16 = (lane >> 5) * 16;      // k-block offset in halves

    // prologue: stage tile 0 into buf 0
    {
        const half8 h0 = *(const half8*)(Wimg + boff0);
        const half8 l0 = *(const half8*)(Wimg + boff0 + 16);
        const half8 h1 = *(const half8*)(Wimg + boff1);
        const half8 l1 = *(const half8*)(Wimg + boff1 + 16);
        const float4 a0 = *(const float4*)Aptr;
        const float4 a1 = *(const float4*)(Aptr + 4);
        *(half8*)&Bb[0][blb0]     = h0;
        *(half8*)&Bb[0][blb0 + 8] = l0;
        *(half8*)&Bb[0][blb1]     = h1;
        *(half8*)&Bb[0][blb1 + 8] = l1;
        half8 ha, la;
        cvt8(a0, a1, ha, la);
        *(half8*)&Ab[0][alb]     = ha;
        *(half8*)&Ab[0][alb + 8] = la;
    }
    __syncthreads();

    floatx16 acc[2][2];
#pragma unroll
    for (int i = 0; i < 2; i++)
#pragma unroll
        for (int j = 0; j < 2; j++)
#pragma unroll
            for (int r = 0; r < 16; r++) acc[i][j][r] = 0.f;

#define MFMA_CLUSTER(i, j)                                                    \
    __builtin_amdgcn_s_setprio(1);                                            \
    _Pragma("unroll")                                                         \
    for (int s = 0; s < 2; s++) {                                             \
        acc[i][j] = __builtin_amdgcn_mfma_f32_32x32x16_f16(                   \
            aL[i][s], bH[j][s], acc[i][j], 0, 0, 0);                          \
        acc[i][j] = __builtin_amdgcn_mfma_f32_32x32x16_f16(                   \
            aH[i][s], bL[j][s], acc[i][j], 0, 0, 0);                          \
        acc[i][j] = __builtin_amdgcn_mfma_f32_32x32x16_f16(                   \
            aH[i][s], bH[j][s], acc[i][j], 0, 0, 0);                          \
    }                                                                         \
    __builtin_amdgcn_s_setprio(0);

    for (int t = 0; t < NT; ++t) {
        const _Float16* Ac = Ab[t & 1];
        const _Float16* Bc = Bb[t & 1];
        _Float16* An = Ab[(t + 1) & 1];
        _Float16* Bn = Bb[(t + 1) & 1];
        const bool pre = (t + 1 < NT);

        half8 aH[2][2], aL[2][2], bH[2][2], bL[2][2];   // [i or j][s]

        // ---- Phase 0: cluster (0,0); issue ALL next-tile global loads ----
        half8 nb0h, nb0l, nb1h, nb1l; float4 na0, na1;
        if (pre) {
            const char* wsrc = Wimg + (size_t)(t + 1) * WTILE_BYTES;
            nb0h = *(const half8*)(wsrc + boff0);
            nb0l = *(const half8*)(wsrc + boff0 + 16);
            nb1h = *(const half8*)(wsrc + boff1);
            nb1l = *(const half8*)(wsrc + boff1 + 16);
            const float* asrc = Aptr + (t + 1) * BK;
            na0 = *(const float4*)asrc;
            na1 = *(const float4*)(asrc + 4);
        }
#pragma unroll
        for (int s = 0; s < 2; s++) {
            const int ao = (wm + r32) * RSTR + s * 32 + kb16;
            aH[0][s] = *(const half8*)&Ac[ao];
            aL[0][s] = *(const half8*)&Ac[ao + 8];
            const int bo = (wn + r32) * RSTR + s * 32 + kb16;
            bH[0][s] = *(const half8*)&Bc[bo];
            bL[0][s] = *(const half8*)&Bc[bo + 8];
        }
        __syncthreads();
        MFMA_CLUSTER(0, 0)
        __syncthreads();

        // ---- Phase 1: cluster (0,1); read B[1] ----
#pragma unroll
        for (int s = 0; s < 2; s++) {
            const int bo = (wn + 32 + r32) * RSTR + s * 32 + kb16;
            bH[1][s] = *(const half8*)&Bc[bo];
            bL[1][s] = *(const half8*)&Bc[bo + 8];
        }
        __syncthreads();
        MFMA_CLUSTER(0, 1)
        __syncthreads();

        // ---- Phase 2: cluster (1,0); read A[1]; B stage-writes ----
#pragma unroll
        for (int s = 0; s < 2; s++) {
            const int ao = (wm + 32 + r32) * RSTR + s * 32 + kb16;
            aH[1][s] = *(const half8*)&Ac[ao];
            aL[1][s] = *(const half8*)&Ac[ao + 8];
        }
        if (pre) {   // consume B loads (in flight since Ph0, ~2 phases cover)
            *(half8*)&Bn[blb0]     = nb0h;
            *(half8*)&Bn[blb0 + 8] = nb0l;
            *(half8*)&Bn[blb1]     = nb1h;
            *(half8*)&Bn[blb1 + 8] = nb1l;
        }
        __syncthreads();
        MFMA_CLUSTER(1, 0)
        __syncthreads();

        // ---- Phase 3: cluster (1,1); A cvt + stage-writes ----
        if (pre) {   // consume A loads (in flight since Ph0, ~3 phases cover)
            half8 ha, la;
            cvt8(na0, na1, ha, la);
            *(half8*)&An[alb]     = ha;
            *(half8*)&An[alb + 8] = la;
        }
        __syncthreads();
        MFMA_CLUSTER(1, 1)
        __syncthreads();
    }
#undef MFMA_CLUSTER

    // epilogue: D col = expert (lane&31), row = (reg&3)+8*(reg>>2)+4*(lane>>5)
    // split-K accumulation via atomicAdd (R3-measured: ~16 MB HBM writes)
#pragma unroll
    for (int i = 0; i < 2; i++)
#pragma unroll
        for (int j = 0; j < 2; j++) {
            const int col = wn + j * 32 + r32;
#pragma unroll
            for (int reg = 0; reg < 16; reg++) {
                const int row = mb + wm + i * 32
                              + (reg & 3) + 8 * (reg >> 2) + 4 * (lane >> 5);
                atomicAdd(&OUT[(size_t)row * NEXPERT + col], acc[i][j][reg]);
            }
        }
}

// ---------------------------------------------------------------------------
// Routing: one wave per token, in-place on d_out (logits -> gate weights).
// Sigmoid fused; exact jax semantics incl. lowest-index tie-breaks.
// ---------------------------------------------------------------------------
__global__ __launch_bounds__(256) void route_kernel(
    float* __restrict__ S, const float* __restrict__ bias)
{
    const int lane = threadIdx.x & 63;
    const int wave = threadIdx.x >> 6;
    const int t    = blockIdx.x * 4 + wave;

    const float4 lg4 = *(const float4*)&S[(size_t)t * NEXPERT + lane * 4];
    const float4 b4  = *(const float4*)&bias[lane * 4];
    float sc[4];
    sc[0] = 1.0f / (1.0f + expf(-lg4.x));
    sc[1] = 1.0f / (1.0f + expf(-lg4.y));
    sc[2] = 1.0f / (1.0f + expf(-lg4.z));
    sc[3] = 1.0f / (1.0f + expf(-lg4.w));
    float swb[4] = { sc[0] + b4.x, sc[1] + b4.y, sc[2] + b4.z, sc[3] + b4.w };

    // per-lane top-2 of 4
    float m1 = -INFINITY, m2 = -INFINITY;
#pragma unroll
    for (int j = 0; j < 4; j++) {
        const float v = swb[j];
        if (v > m1)      { m2 = m1; m1 = v; }
        else if (v > m2) { m2 = v; }
    }
    // merge across the 8 lanes of my group
#pragma unroll
    for (int s = 1; s < 8; s <<= 1) {
        const float o1 = __shfl_xor(m1, s, 64);
        const float o2 = __shfl_xor(m2, s, 64);
        const float hi = fmaxf(m1, o1);
        const float lo = fminf(m1, o1);
        m2 = fmaxf(lo, fmaxf(m2, o2));
        m1 = hi;
    }
    const float gs = m1 + m2;

    // top-4 groups by rank (tie -> lower group index)
    float gsc[NGROUP];
#pragma unroll
    for (int g = 0; g < NGROUP; g++) gsc[g] = __shfl(gs, g * 8, 64);
    const int myg = lane >> 3;
    int rank = 0;
#pragma unroll
    for (int g = 0; g < NGROUP; g++)
        rank += (gsc[g] > gs) || (gsc[g] == gs && g < myg);
    const bool kept = (rank < TOPKG);

    float v[4];
#pragma unroll
    for (int j = 0; j < 4; j++) v[j] = kept ? swb[j] : 0.0f;

    // top-8 experts: 8 rounds of wave argmax (lowest idx on ties)
    float sum = 0.0f;
    int selmask = 0;
    for (int r = 0; r < TOPK; r++) {
        float bv = -INFINITY;
        int   bi = 0x7fffffff;
#pragma unroll
        for (int j = 0; j < 4; j++) {
            const bool avail = ((selmask >> j) & 1) == 0;
            if (avail && v[j] > bv) { bv = v[j]; bi = lane * 4 + j; }
        }
#pragma unroll
        for (int s = 1; s < 64; s <<= 1) {
            const float ov = __shfl_xor(bv, s, 64);
            const int   oi = __shfl_xor(bi, s, 64);
            if (ov > bv || (ov == bv && oi < bi)) { bv = ov; bi = oi; }
        }
        const int wl = bi >> 2, wj = bi & 3;
        const float mysc = (wj == 0) ? sc[0] : (wj == 1) ? sc[1]
                         : (wj == 2) ? sc[2] : sc[3];
        sum += __shfl(mysc, wl, 64);
        if (lane == wl) selmask |= (1 << wj);
    }

    const float rcp = SCALE / (sum + 1e-20f);
    float4 o;
    o.x = (selmask & 1) ? sc[0] * rcp : 0.0f;
    o.y = (selmask & 2) ? sc[1] * rcp : 0.0f;
    o.z = (selmask & 4) ? sc[2] * rcp : 0.0f;
    o.w = (selmask & 8) ? sc[3] * rcp : 0.0f;
    *(float4*)&S[(size_t)t * NEXPERT + lane * 4] = o;
}

extern "C" void kernel_launch(void* const* d_in, const int* in_sizes, int n_in,
                              void* d_out, int out_size, void* d_ws, size_t ws_size,
                              hipStream_t stream) {
    const float* X    = (const float*)d_in[0];   // [8192, 7168]
    const float* W    = (const float*)d_in[1];   // [256, 7168]
    const float* bias = (const float*)d_in[2];   // [256]
    float* out = (float*)d_out;                  // [8192, 256]
    // d_ws: 4*56 tiles x 32 KB = 7,340,032 B of pre-split W images. The
    // harness poison-fills d_ws every iteration regardless of use (R0-R2
    // evidence: identical 917 MB fill) -> using it is free; we rewrite our
    // slice before the GEMM reads it.
    char* ws = (char*)d_ws; (void)ws_size;

    zero_kernel<<<(TOKENS * NEXPERT / 4) / 256, 256, 0, stream>>>(out);
    wsplit_kernel<<<NEXPERT, 896, 0, stream>>>(W, ws);
    dim3 ggrid(TOKENS / BM, KSPLIT);             // (64, 4) = 256 blocks, 1/CU
    gate_gemm_kernel<<<ggrid, 512, 0, stream>>>(X, ws, out);
    route_kernel<<<TOKENS / 4, 256, 0, stream>>>(out, bias);
}

// Round 4
// 401.931 us; speedup vs baseline: 1.0440x; 1.0440x over previous
//
#include <hip/hip_runtime.h>
#include <math.h>

#define TOKENS   8192
#define HIDDEN   7168
#define NEXPERT  256
#define NGROUP   8
#define TOPKG    4
#define TOPK     8
#define SCALE    2.5f

// R10: occupancy-first restructure. R9 post-mortem: 4-phase/8-barrier at
// 1 block/CU serialized (dependent 6-MFMA chains, no independent work to
// hide barriers) -> 173 us. R8 (137 us) won via 2 independent blocks/CU.
// This round pushes that lever to 4 blocks/CU:
//   - SINGLE-buffered LDS 36 KB (was 2x36=72) -> 4 blocks/CU by LDS.
//   - KSPLIT=8 -> grid (2,64,8) = 1024 blocks = exactly 4/CU resident.
//   - Per K-tile: {stage-writes; barrier; issue t+1 loads; frag reads +
//     48 MFMA (16 independent acc chains); barrier}. Same barriers/block
//     as R8 (56), half the tiles, 4 independent blocks hide every stall.
//   - Register staging (R7 lesson: register-destined global loads are NOT
//     drained at __syncthreads; they wait at first use, a full MFMA phase
//     later). B from the R8-proven pre-split W image (zero cvt VALU).
// MFMA 16x16x32_f16, product order al*bh + ah*bl + ah*bh (R6/R8-proven).
#define BM 128
#define BN 128
#define BK 32
#define KSPLIT 8
#define KPB (HIDDEN / KSPLIT)   // 896
#define NT  (KPB / BK)          // 28
#define TILE_BYTES 16384        // W image tile: 128 rows x 4 octets x 32 B

// LDS layout (halves): addr(row,k,hl) = row*72 + (k>>3)*16 + hl*8 + (k&7).
// Row stride 72 halves = 144 B: 16B-aligned b128 frags. Wave64 b128 access
// has an 8-lanes-per-start-bank floor in any 16B-aligned layout (R7
// analysis) -> the ~7M conflict counter is structural, not fixable.
#define RSTR 72

typedef _Float16 half8 __attribute__((ext_vector_type(8)));
typedef _Float16 half4 __attribute__((ext_vector_type(4)));
typedef float    floatx4 __attribute__((ext_vector_type(4)));

// fp32 -> fp16 hi/lo split, store h4 at octet +0..7, l4 at +8..15
__device__ __forceinline__ void cvt_store(_Float16* __restrict__ H,
                                          int row, int k0, float4 v) {
    half4 h, l;
    h[0] = (_Float16)v.x; h[1] = (_Float16)v.y;
    h[2] = (_Float16)v.z; h[3] = (_Float16)v.w;
    l[0] = (_Float16)(v.x - (float)h[0]);
    l[1] = (_Float16)(v.y - (float)h[1]);
    l[2] = (_Float16)(v.z - (float)h[2]);
    l[3] = (_Float16)(v.w - (float)h[3]);
    const int base = row * RSTR + ((k0 >> 3) << 4) + (k0 & 7);
    *(half4*)&H[base]     = h;
    *(half4*)&H[base + 8] = l;
}

// fp32x8 -> fp16 hi/lo split (same RNE bits; used by wsplit)
__device__ __forceinline__ void cvt8(const float4 a, const float4 b,
                                     half8& h, half8& l) {
    h[0] = (_Float16)a.x; h[1] = (_Float16)a.y;
    h[2] = (_Float16)a.z; h[3] = (_Float16)a.w;
    h[4] = (_Float16)b.x; h[5] = (_Float16)b.y;
    h[6] = (_Float16)b.z; h[7] = (_Float16)b.w;
    l[0] = (_Float16)(a.x - (float)h[0]); l[1] = (_Float16)(a.y - (float)h[1]);
    l[2] = (_Float16)(a.z - (float)h[2]); l[3] = (_Float16)(a.w - (float)h[3]);
    l[4] = (_Float16)(b.x - (float)h[4]); l[5] = (_Float16)(b.y - (float)h[5]);
    l[6] = (_Float16)(b.z - (float)h[6]); l[7] = (_Float16)(b.w - (float)h[7]);
}

// ---------------------------------------------------------------------------
// W pre-split + OUT zeroing fused (one fewer dispatch).
// Tile (nb,kz,t): 128 rows x 4 octets x (hi8|lo8) = 16 KB, matching GEMM
// B-staging reads exactly. One block per expert, 896 threads, one k-octet
// each. OUT zeroed grid-stride (poisoned 0xAA each iter; atomics need 0).
// ---------------------------------------------------------------------------
__global__ __launch_bounds__(896) void wsplit_kernel(
    const float* __restrict__ W, char* __restrict__ WS, float* __restrict__ O)
{
    const int gt = blockIdx.x * 896 + threadIdx.x;
#pragma unroll
    for (int i = 0; i < 3; i++) {
        const int idx = gt + i * (NEXPERT * 896);
        if (idx < TOKENS * NEXPERT / 4)
            *(float4*)&O[(size_t)idx * 4] = float4{0.f, 0.f, 0.f, 0.f};
    }

    const int e  = blockIdx.x;          // expert 0..255
    const int og = threadIdx.x;         // k-octet within expert, 0..895
    const float4 a = *(const float4*)&W[(size_t)e * HIDDEN + og * 8];
    const float4 b = *(const float4*)&W[(size_t)e * HIDDEN + og * 8 + 4];
    half8 h, l;
    cvt8(a, b, h, l);

    const int kz = og / (KPB / 8);      // k-split  0..7  (112 octets per kz)
    const int tt = (og % (KPB / 8)) >> 2;  // k-tile 0..27
    const int oc = og & 3;              // octet    0..3
    const int row = e & 127, nb = e >> 7;
    char* p = WS + (size_t)((nb * KSPLIT + kz) * NT + tt) * TILE_BYTES
            + (row * 4 + oc) * 32;
    *(half8*)p        = h;
    *(half8*)(p + 16) = l;
}

// ---------------------------------------------------------------------------
// Gate GEMM via fp16-split 3-product MFMA: x = xh + xl (fp16 RNE),
// logit = sum al*bh + ah*bl + ah*bh (fp32 acc, R6/R8-proven order).
// Single-buffer LDS, 2 barriers/tile, 4 blocks/CU. Next-tile global loads
// issued right after the write-visibility barrier -> ~a full frag-read+MFMA
// phase (500+ cy) in flight before the vmcnt wait at next stage-write.
// ---------------------------------------------------------------------------
__global__ __launch_bounds__(256, 4) void gate_gemm_kernel(
    const float* __restrict__ X, const char* __restrict__ WS,
    float* __restrict__ OUT)
{
    __shared__ _Float16 Ab[BM * RSTR];   // 18 KB
    __shared__ _Float16 Bb[BN * RSTR];   // 18 KB  -> 36 KB total

    const int tid = threadIdx.x;
    const int nb  = blockIdx.x * BN;
    const int mb  = blockIdx.y * BM;
    const int kb  = blockIdx.z * KPB;

    // A staging map (R8): thread t takes rows q*32 + (t>>3), k0 = (t&7)*4
    const int srow = tid >> 3;            // 0..31 (+q*32)
    const int sk0  = (tid & 7) * 4;       // 0..28
    const float* Aptr = X + (size_t)(mb + srow) * HIDDEN + kb + sk0;

    // B staging map (R8): pair p = tid + 256*s -> row = p>>2, oct = p&3;
    // 32 B contiguous (hi8|lo8) per pair in the packed W image.
    const char* Wimg =
        WS + (size_t)((blockIdx.x * KSPLIT + blockIdx.z) * NT) * TILE_BYTES;
    const int bbase[2] = { (tid >> 2) * RSTR + (tid & 3) * 16,
                           ((tid >> 2) + 64) * RSTR + (tid & 3) * 16 };

    // prologue: issue tile-0 global loads (register-destined)
    float4 av[4];
    half8  nh[2], nl[2];
#pragma unroll
    for (int q = 0; q < 4; q++)
        av[q] = *(const float4*)(Aptr + (size_t)(q * 32) * HIDDEN);
#pragma unroll
    for (int s = 0; s < 2; s++) {
        const char* src = Wimg + (tid + 256 * s) * 32;
        nh[s] = *(const half8*)src;
        nl[s] = *(const half8*)(src + 16);
    }

    // 4 waves as 2x2; wave tile 64m x 64n; 4x4 16x16 frags per wave
    const int lane = tid & 63, wave = tid >> 6;
    const int wm = (wave >> 1) * 64, wn = (wave & 1) * 64;
    const int fr = lane & 15, quad = lane >> 4;

    floatx4 acc[4][4];
#pragma unroll
    for (int i = 0; i < 4; i++)
#pragma unroll
        for (int j = 0; j < 4; j++) acc[i][j] = floatx4{0.f, 0.f, 0.f, 0.f};

    for (int t = 0; t < NT; t++) {
        // stage tile t (vmcnt waits here; loads have been in flight since
        // the previous iteration's post-barrier issue point)
#pragma unroll
        for (int q = 0; q < 4; q++)
            cvt_store(Ab, q * 32 + srow, sk0, av[q]);
#pragma unroll
        for (int s = 0; s < 2; s++) {
            *(half8*)&Bb[bbase[s]]     = nh[s];
            *(half8*)&Bb[bbase[s] + 8] = nl[s];
        }

        __syncthreads();   // stage-writes visible to all waves

        // issue next tile's loads now; they fly across the whole MFMA phase
        if (t + 1 < NT) {
            const int o = (t + 1) * BK;
#pragma unroll
            for (int q = 0; q < 4; q++)
                av[q] = *(const float4*)(Aptr + o + (size_t)(q * 32) * HIDDEN);
            const char* srcT = Wimg + (size_t)(t + 1) * TILE_BYTES;
#pragma unroll
            for (int s = 0; s < 2; s++) {
                const char* src = srcT + (tid + 256 * s) * 32;
                nh[s] = *(const half8*)src;
                nl[s] = *(const half8*)(src + 16);
            }
        }

        half8 ah[4], al[4];
#pragma unroll
        for (int i = 0; i < 4; i++) {
            const int a = (wm + i * 16 + fr) * RSTR + quad * 16;
            ah[i] = *(const half8*)&Ab[a];
            al[i] = *(const half8*)&Ab[a + 8];
        }
#pragma unroll
        for (int j = 0; j < 4; j++) {
            const int b = (wn + j * 16 + fr) * RSTR + quad * 16;
            const half8 bh = *(const half8*)&Bb[b];
            const half8 bl = *(const half8*)&Bb[b + 8];
#pragma unroll
            for (int i = 0; i < 4; i++) {
                acc[i][j] = __builtin_amdgcn_mfma_f32_16x16x32_f16(
                    al[i], bh, acc[i][j], 0, 0, 0);
                acc[i][j] = __builtin_amdgcn_mfma_f32_16x16x32_f16(
                    ah[i], bl, acc[i][j], 0, 0, 0);
                acc[i][j] = __builtin_amdgcn_mfma_f32_16x16x32_f16(
                    ah[i], bh, acc[i][j], 0, 0, 0);
            }
        }

        __syncthreads();   // frag reads done; buffer free for next writes
    }

    // epilogue: D row = token (quad*4+reg), col = expert (lane&15);
    // split-K accumulation via atomicAdd (R3-proven pattern; 8-way now)
#pragma unroll
    for (int i = 0; i < 4; i++)
#pragma unroll
        for (int j = 0; j < 4; j++) {
            const int col = nb + wn + j * 16 + fr;
#pragma unroll
            for (int r = 0; r < 4; r++) {
                const int row = mb + wm + i * 16 + quad * 4 + r;
                atomicAdd(&OUT[(size_t)row * NEXPERT + col], acc[i][j][r]);
            }
        }
}

// ---------------------------------------------------------------------------
// Routing: one wave per token, in-place on d_out (logits -> gate weights).
// Sigmoid fused; exact jax semantics incl. lowest-index tie-breaks.
// ---------------------------------------------------------------------------
__global__ __launch_bounds__(256) void route_kernel(
    float* __restrict__ S, const float* __restrict__ bias)
{
    const int lane = threadIdx.x & 63;
    const int wave = threadIdx.x >> 6;
    const int t    = blockIdx.x * 4 + wave;

    const float4 lg4 = *(const float4*)&S[(size_t)t * NEXPERT + lane * 4];
    const float4 b4  = *(const float4*)&bias[lane * 4];
    float sc[4];
    sc[0] = 1.0f / (1.0f + expf(-lg4.x));
    sc[1] = 1.0f / (1.0f + expf(-lg4.y));
    sc[2] = 1.0f / (1.0f + expf(-lg4.z));
    sc[3] = 1.0f / (1.0f + expf(-lg4.w));
    float swb[4] = { sc[0] + b4.x, sc[1] + b4.y, sc[2] + b4.z, sc[3] + b4.w };

    // per-lane top-2 of 4
    float m1 = -INFINITY, m2 = -INFINITY;
#pragma unroll
    for (int j = 0; j < 4; j++) {
        const float v = swb[j];
        if (v > m1)      { m2 = m1; m1 = v; }
        else if (v > m2) { m2 = v; }
    }
    // merge across the 8 lanes of my group
#pragma unroll
    for (int s = 1; s < 8; s <<= 1) {
        const float o1 = __shfl_xor(m1, s, 64);
        const float o2 = __shfl_xor(m2, s, 64);
        const float hi = fmaxf(m1, o1);
        const float lo = fminf(m1, o1);
        m2 = fmaxf(lo, fmaxf(m2, o2));
        m1 = hi;
    }
    const float gs = m1 + m2;

    // top-4 groups by rank (tie -> lower group index)
    float gsc[NGROUP];
#pragma unroll
    for (int g = 0; g < NGROUP; g++) gsc[g] = __shfl(gs, g * 8, 64);
    const int myg = lane >> 3;
    int rank = 0;
#pragma unroll
    for (int g = 0; g < NGROUP; g++)
        rank += (gsc[g] > gs) || (gsc[g] == gs && g < myg);
    const bool kept = (rank < TOPKG);

    float v[4];
#pragma unroll
    for (int j = 0; j < 4; j++) v[j] = kept ? swb[j] : 0.0f;

    // top-8 experts: 8 rounds of wave argmax (lowest idx on ties)
    float sum = 0.0f;
    int selmask = 0;
    for (int r = 0; r < TOPK; r++) {
        float bv = -INFINITY;
        int   bi = 0x7fffffff;
#pragma unroll
        for (int j = 0; j < 4; j++) {
            const bool avail = ((selmask >> j) & 1) == 0;
            if (avail && v[j] > bv) { bv = v[j]; bi = lane * 4 + j; }
        }
#pragma unroll
        for (int s = 1; s < 64; s <<= 1) {
            const float ov = __shfl_xor(bv, s, 64);
            const int   oi = __shfl_xor(bi, s, 64);
            if (ov > bv || (ov == bv && oi < bi)) { bv = ov; bi = oi; }
        }
        const int wl = bi >> 2, wj = bi & 3;
        const float mysc = (wj == 0) ? sc[0] : (wj == 1) ? sc[1]
                         : (wj == 2) ? sc[2] : sc[3];
        sum += __shfl(mysc, wl, 64);
        if (lane == wl) selmask |= (1 << wj);
    }

    const float rcp = SCALE / (sum + 1e-20f);
    float4 o;
    o.x = (selmask & 1) ? sc[0] * rcp : 0.0f;
    o.y = (selmask & 2) ? sc[1] * rcp : 0.0f;
    o.z = (selmask & 4) ? sc[2] * rcp : 0.0f;
    o.w = (selmask & 8) ? sc[3] * rcp : 0.0f;
    *(float4*)&S[(size_t)t * NEXPERT + lane * 4] = o;
}

extern "C" void kernel_launch(void* const* d_in, const int* in_sizes, int n_in,
                              void* d_out, int out_size, void* d_ws, size_t ws_size,
                              hipStream_t stream) {
    const float* X    = (const float*)d_in[0];   // [8192, 7168]
    const float* W    = (const float*)d_in[1];   // [256, 7168]
    const float* bias = (const float*)d_in[2];   // [256]
    float* out = (float*)d_out;                  // [8192, 256]
    // d_ws: 2*8*28 tiles x 16 KB = 7,340,032 B of pre-split W images. The
    // harness poison-fills d_ws every iteration regardless of use (R0-R2
    // evidence) -> using it is free; we rewrite our slice before the GEMM.
    char* ws = (char*)d_ws; (void)ws_size;

    wsplit_kernel<<<NEXPERT, 896, 0, stream>>>(W, ws, out);
    dim3 ggrid(NEXPERT / BN, TOKENS / BM, KSPLIT);  // (2,64,8) = 1024 = 4/CU
    gate_gemm_kernel<<<ggrid, 256, 0, stream>>>(X, ws, out);
    route_kernel<<<TOKENS / 4, 256, 0, stream>>>(out, bias);
}